// Round 5
// baseline (114.298 us; speedup 1.0000x reference)
//
#include <hip/hip_runtime.h>
#include <math.h>

#ifndef M_PI
#define M_PI 3.14159265358979323846
#endif

#define T_LEN   262144
#define NBATCH  64
#define STEP    171
#define NSEG    1531          // (262144-512)/171 + 1
#define NPAIR   766           // ceil(1531/2); last pair has zero imag segment
#define WPB     128           // waves per batch -> 8192 waves total
#define HI_BIN  244           // exclusive upper band bin

typedef float v2f __attribute__((ext_vector_type(2)));

__device__ __forceinline__ int bitrev3(int r) {
    return ((r & 1) << 2) | (r & 2) | ((r & 4) >> 2);
}

// ---- gfx950 cross-lane helpers ----
// NOT volatile: pure dataflow, scheduler may move loads/ops across them.
__device__ __forceinline__ void pswap32(float& a, float& b) {
    asm("v_permlane32_swap_b32 %0, %1" : "+v"(a), "+v"(b));
}
__device__ __forceinline__ void pswap16(float& a, float& b) {
    asm("v_permlane16_swap_b32 %0, %1" : "+v"(a), "+v"(b));
}
template <int CTRL>
__device__ __forceinline__ float dppf(float x) {   // DPP cross-lane (VALU pipe)
    return __int_as_float(__builtin_amdgcn_mov_dpp(__float_as_int(x), CTRL, 0xF, 0xF, true));
}
template <int OFF>
__device__ __forceinline__ float swz(float x) {    // ds_swizzle bit-mode (DS pipe)
    return __int_as_float(__builtin_amdgcn_ds_swizzle(__float_as_int(x), OFF));
}

// complex rotate: z * (c + i s), w = (c, s) packed. Exactly 2 VOP3P instrs.
__device__ __forceinline__ v2f cmul(v2f z, v2f w) {
    v2f t, d;
    asm("v_pk_mul_f32 %0, %1, %2 op_sel_hi:[1,0]"
        : "=v"(t) : "v"(z), "v"(w));
    asm("v_pk_fma_f32 %0, %1, %2, %3 op_sel:[1,1,0] op_sel_hi:[0,1,1] neg_lo:[1,0,0]"
        : "=v"(d) : "v"(z), "v"(w), "v"(t));
    return d;
}

// volatile pin: opaque def -> cannot be rematerialized or sunk into the loop
#define PINV(x) asm volatile("" : "+v"(x))

// ws layout: [0, 8192) per-wave partial band sums
__global__ __launch_bounds__(256, 4) void fft_band_k(const float* __restrict__ x,
                                                     float* __restrict__ ws) {
    const int L      = threadIdx.x & 63;
    const int waveId = (int)(blockIdx.x * 256 + threadIdx.x) >> 6;
    const int b      = waveId >> 7;           // / WPB
    const int winb   = waveId & (WPB - 1);

    // ---- start first prefetch before the (expensive) constant setup ----
    const float* pbase = x + (size_t)b * T_LEN + (size_t)(2 * winb) * STEP + L;
    float a[8], bb[8];
#pragma unroll
    for (int r = 0; r < 8; ++r) a[r] = pbase[64 * r];
#pragma unroll
    for (int r = 0; r < 8; ++r) bb[r] = pbase[64 * r + STEP];  // 2*winb+1 <= 255 < NSEG always

    // ---- per-wave loop-invariant constants (volatile-pinned vs remat) ----
    v2f wvp[8];
#pragma unroll
    for (int r = 0; r < 8; ++r) {
        float n = (float)(L + 64 * r);
        float w = 0.54f - 0.46f * __cosf((float)(2.0 * M_PI / 512.0) * n);
        wvp[r] = (v2f){w, w};
        PINV(wvp[r]);
    }
    float wt[8];
#pragma unroll
    for (int p = 0; p < 8; ++p) {
        int k = 4 * ((L >> 5) & 1) + 2 * ((L >> 4) & 1) + ((p >> 2) & 1)
              + 8 * ((p & 1) + 2 * ((p >> 1) & 1) + 4 * ((L >> 3) & 1)
                     + 8 * ((L >> 2) & 1) + 16 * ((L >> 1) & 1) + 32 * (L & 1));
        int mb = (k <= 256) ? k : 512 - k;
        float wgt = 0.0f;
        if (mb >= 1 && mb < HI_BIN) {
            float f   = (float)mb * (3152.0f / 512.0f);
            float fsq = f * f;
            float num = 1.48693636e8f * fsq * fsq;
            float d1  = fsq + 424.36f;
            float d2  = fsq + 11599.29f;
            float d3  = fsq + 544496.41f;
            float d4  = fsq + 1.48693636e8f;
            float ratio = (num / (d1 * d4)) * rsqrtf(d2 * d3);
            wgt = ratio * ratio * 1.6141422e-9f;   // ratio^2 * 10^0.2 / (winpow*FS*nseg)
        }
        wt[p] = wgt;
        PINV(wt[p]);
    }
    // mid twiddles (c,s) = e^{-2pi i * bitrev3(r) * L / 512}
    v2f M[8];
#pragma unroll
    for (int r = 1; r < 8; ++r) {
        float ang = (float)(-2.0 * M_PI / 512.0) * (float)(bitrev3(r) * L);
        float s, c; __sincosf(ang, &s, &c);
        M[r] = (v2f){c, s};
        PINV(M[r]);
    }
    // cross-lane stage twiddles
    float c32, s32, c16, s16;
    __sincosf((float)(-2.0 * M_PI) * (float)(L & 31) / 64.0f, &s32, &c32);
    __sincosf((float)(-2.0 * M_PI) * (float)(L & 15) / 32.0f, &s16, &c16);
    v2f W32 = (v2f){c32, s32};
    v2f W16 = (v2f){c16, s16};
    v2f W8, W4, W2, g8v, g4v, g2v, g1v;
    if (L & 8) { float s, c; __sincosf((float)(-2.0 * M_PI) * (float)(L & 7) / 16.0f, &s, &c);
                 W8 = (v2f){c, s}; g8v = (v2f){-1.0f, -1.0f}; }
    else       { W8 = (v2f){1.0f, 0.0f}; g8v = (v2f){1.0f, 1.0f}; }
    if (L & 4) { float s, c; __sincosf((float)(-2.0 * M_PI) * (float)(L & 3) / 8.0f, &s, &c);
                 W4 = (v2f){c, s}; g4v = (v2f){-1.0f, -1.0f}; }
    else       { W4 = (v2f){1.0f, 0.0f}; g4v = (v2f){1.0f, 1.0f}; }
    if (L & 2) { W2 = (L & 1) ? (v2f){0.0f, -1.0f} : (v2f){1.0f, 0.0f};
                 g2v = (v2f){-1.0f, -1.0f}; }
    else       { W2 = (v2f){1.0f, 0.0f}; g2v = (v2f){1.0f, 1.0f}; }
    g1v = (L & 1) ? (v2f){-1.0f, -1.0f} : (v2f){1.0f, 1.0f};
    PINV(W32); PINV(W16); PINV(W8); PINV(W4); PINV(W2);
    PINV(g8v); PINV(g4v); PINV(g2v); PINV(g1v);

    const float C707 = 0.70710678118654752f;
    v2f W81 = (v2f){C707, -C707};
    v2f W83 = (v2f){-C707, -C707};
    v2f WNI = (v2f){0.0f, -1.0f};
    PINV(W81); PINV(W83); PINV(WNI);

    v2f acc2 = (v2f){0.0f, 0.0f};

    for (int p = winb; p < NPAIR; p += WPB) {
        // ---- consume prefetched samples: window + pack ----
        v2f z[8];
#pragma unroll
        for (int r = 0; r < 8; ++r) z[r] = (v2f){a[r], bb[r]} * wvp[r];

        // ---- prefetch next iteration (overlaps with FFT below) ----
        const int pn = p + WPB;
        if (pn < NPAIR) {                    // wave-uniform
            pbase += 2 * WPB * STEP;
#pragma unroll
            for (int r = 0; r < 8; ++r) a[r] = pbase[64 * r];
            if (2 * pn + 1 < NSEG) {         // wave-uniform; false only at p=765
#pragma unroll
                for (int r = 0; r < 8; ++r) bb[r] = pbase[64 * r + STEP];
            } else {
#pragma unroll
                for (int r = 0; r < 8; ++r) bb[r] = 0.0f;
            }
        }

        // ---- per-lane radix-2 DIF FFT-8 over registers (packed complex) ----
        {
            v2f d0 = z[0] - z[4]; z[0] += z[4];
            v2f d1 = z[1] - z[5]; z[1] += z[5];
            v2f d2 = z[2] - z[6]; z[2] += z[6];
            v2f d3 = z[3] - z[7]; z[3] += z[7];
            z[4] = d0;
            z[5] = cmul(d1, W81);
            z[6] = cmul(d2, WNI);
            z[7] = cmul(d3, W83);
            v2f t;
            t = z[0] - z[2]; z[0] += z[2]; z[2] = t;
            t = z[1] - z[3]; z[1] += z[3]; z[3] = cmul(t, WNI);
            t = z[4] - z[6]; z[4] += z[6]; z[6] = t;
            t = z[5] - z[7]; z[5] += z[7]; z[7] = cmul(t, WNI);
#pragma unroll
            for (int g = 0; g < 8; g += 2) {
                t = z[g] - z[g + 1]; z[g] += z[g + 1]; z[g + 1] = t;
            }
        }

        // ---- mid twiddle ----
#pragma unroll
        for (int r = 1; r < 8; ++r) z[r] = cmul(z[r], M[r]);

        // ---- cross-lane FFT-64 ----
        // m=32: permlane32_swap two-reg trick (VALU)
#pragma unroll
        for (int q = 0; q < 8; q += 2) {
            float a0 = z[q].x, a1 = z[q].y, b0 = z[q + 1].x, b1 = z[q + 1].y;
            pswap32(a0, b0); pswap32(a1, b1);
            v2f A = (v2f){a0, a1}, B = (v2f){b0, b1};
            v2f s = A + B, d = A - B;
            z[q] = s; z[q + 1] = cmul(d, W32);
        }
        // m=16: permlane16_swap trick, pairs (q, q+2)
        {
            const int qs[4] = {0, 1, 4, 5};
#pragma unroll
            for (int t2 = 0; t2 < 4; ++t2) {
                const int q = qs[t2];
                float a0 = z[q].x, a1 = z[q].y, b0 = z[q + 2].x, b1 = z[q + 2].y;
                pswap16(a0, b0); pswap16(a1, b1);
                v2f A = (v2f){a0, a1}, B = (v2f){b0, b1};
                v2f s = A + B, d = A - B;
                z[q] = s; z[q + 2] = cmul(d, W16);
            }
        }
        // m=8: DPP row_ror:8 == lane xor 8 (VALU pipe)
#pragma unroll
        for (int q = 0; q < 8; ++q) {
            v2f pp = (v2f){dppf<0x128>(z[q].x), dppf<0x128>(z[q].y)};
            v2f n = g8v * z[q] + pp;
            z[q] = cmul(n, W8);
        }
        // m=4: ds_swizzle xor 4 (only remaining DS traffic; DS pipe is idle)
#pragma unroll
        for (int q = 0; q < 8; ++q) {
            v2f pp = (v2f){swz<0x101F>(z[q].x), swz<0x101F>(z[q].y)};
            v2f n = g4v * z[q] + pp;
            z[q] = cmul(n, W4);
        }
        // m=2: quad_perm [2,3,0,1]
#pragma unroll
        for (int q = 0; q < 8; ++q) {
            v2f pp = (v2f){dppf<0x4E>(z[q].x), dppf<0x4E>(z[q].y)};
            v2f n = g2v * z[q] + pp;
            z[q] = cmul(n, W2);
        }
        // m=1: quad_perm [1,0,3,2], tw = 1, fused weighted-energy (packed acc)
#pragma unroll
        for (int q = 0; q < 8; ++q) {
            v2f pp = (v2f){dppf<0xB1>(z[q].x), dppf<0xB1>(z[q].y)};
            v2f n = g1v * z[q] + pp;
            v2f e = n * n;
            acc2 += (v2f){wt[q], wt[q]} * e;
        }
    }

    float acc = acc2.x + acc2.y;
    // wave reduction -> one uncontended store per wave
#pragma unroll
    for (int off = 32; off >= 1; off >>= 1) acc += __shfl_xor(acc, off, 64);
    if (L == 0) ws[waveId] = acc;
}

__global__ void finalize_k(const float* __restrict__ ws, float* __restrict__ out) {
    __shared__ float red[256];
    int t = threadIdx.x;          // 256 threads
    int b = t & 63, g = t >> 6;   // 4 chunks of 32 partials per batch
    float s = 0.0f;
    for (int i = 0; i < 32; ++i) s += ws[b * 128 + g * 32 + i];
    red[t] = s;
    __syncthreads();
    if (t < 64) {
        float band = red[t] + red[t + 64] + red[t + 128] + red[t + 192];
        float lv = 10.0f * log10f(band);
#pragma unroll
        for (int off = 32; off >= 1; off >>= 1) lv += __shfl_xor(lv, off, 64);
        if (t == 0) out[0] = lv * (1.0f / 64.0f);
    }
}

extern "C" void kernel_launch(void* const* d_in, const int* in_sizes, int n_in,
                              void* d_out, int out_size, void* d_ws, size_t ws_size,
                              hipStream_t stream) {
    const float* x = (const float*)d_in[0];
    float* out = (float*)d_out;
    float* ws  = (float*)d_ws;
    fft_band_k<<<(NBATCH * WPB) / 4, 256, 0, stream>>>(x, ws);
    finalize_k<<<1, 256, 0, stream>>>(ws, out);
}

// Round 6
// 106.009 us; speedup vs baseline: 1.0782x; 1.0782x over previous
//
#include <hip/hip_runtime.h>
#include <math.h>

#ifndef M_PI
#define M_PI 3.14159265358979323846
#endif

#define T_LEN   262144
#define NBATCH  64
#define STEP    171
#define NSEG    1531          // (262144-512)/171 + 1
#define NPAIR   766           // ceil(1531/2); last pair has zero imag segment
#define WPB     128           // waves per batch -> 8192 waves total
#define HI_BIN  244           // exclusive upper band bin

typedef float v2f __attribute__((ext_vector_type(2)));

__device__ __forceinline__ int bitrev3(int r) {
    return ((r & 1) << 2) | (r & 2) | ((r & 4) >> 2);
}

// ---- gfx950 cross-lane helpers (volatile: proven-good R4 config) ----
__device__ __forceinline__ void pswap32(float& a, float& b) {
    asm volatile("v_permlane32_swap_b32 %0, %1" : "+v"(a), "+v"(b));
}
__device__ __forceinline__ void pswap16(float& a, float& b) {
    asm volatile("v_permlane16_swap_b32 %0, %1" : "+v"(a), "+v"(b));
}
template <int CTRL>
__device__ __forceinline__ float dppf(float x) {   // DPP cross-lane (VALU pipe)
    return __int_as_float(__builtin_amdgcn_mov_dpp(__float_as_int(x), CTRL, 0xF, 0xF, true));
}

// complex rotate: z * (c + i s), w = (c, s) packed. 2 VOP3P instrs.
__device__ __forceinline__ v2f cmul(v2f z, v2f w) {
    v2f t, d;
    asm("v_pk_mul_f32 %0, %1, %2 op_sel_hi:[1,0]"
        : "=v"(t) : "v"(z), "v"(w));
    asm("v_pk_fma_f32 %0, %1, %2, %3 op_sel:[1,1,0] op_sel_hi:[0,1,1] neg_lo:[1,0,0]"
        : "=v"(d) : "v"(z), "v"(w), "v"(t));
    return d;
}
// z * (-i) = (y, -x): single pk_mul with op_sel; m = (1.0, -1.0)
__device__ __forceinline__ v2f cmulNI(v2f z, v2f m) {
    v2f d;
    asm("v_pk_mul_f32 %0, %1, %2 op_sel:[1,0] op_sel_hi:[0,1]"
        : "=v"(d) : "v"(z), "v"(m));
    return d;
}

// volatile pin: opaque def -> cannot be rematerialized or sunk into the loop
#define PINV(x) asm volatile("" : "+v"(x))

// ws layout: [0, 8192) per-wave partial band sums
__global__ __launch_bounds__(256, 4) void fft_band_k(const float* __restrict__ x,
                                                     float* __restrict__ ws) {
    // per-wave private transpose scratch: 8 rows x 132 words (528 B) = 4224 B/wave
    __shared__ __align__(16) char ldsc[4 * 4224];

    const int L      = threadIdx.x & 63;
    const int wib    = threadIdx.x >> 6;
    const int waveId = (int)(blockIdx.x * 256 + threadIdx.x) >> 6;
    const int b      = waveId >> 7;           // / WPB
    const int winb   = waveId & (WPB - 1);

    char* wptr = ldsc + wib * 4224 + 8 * L;                            // + 528*p imm
    char* rptr = ldsc + wib * 4224 + 528 * (L & 7) + 8 * (L & 0x38);   // + 8*rho imm

    // ---- per-wave loop-invariant constants (volatile-pinned vs remat) ----
    v2f wvp[8];
#pragma unroll
    for (int r = 0; r < 8; ++r) {
        float n = (float)(L + 64 * r);
        float w = 0.54f - 0.46f * __cosf((float)(2.0 * M_PI / 512.0) * n);
        wvp[r] = (v2f){w, w};
        PINV(wvp[r]);
    }
    // weights at final (reg rho, lane L): k = L2 + 2*L4 + 4*L5 + 8*L0 + 16*L1 + 32*L3 + 64*bitrev3(rho)
    float wt[8];
#pragma unroll
    for (int p = 0; p < 8; ++p) {
        int k = ((L >> 2) & 1) + 2 * ((L >> 4) & 1) + 4 * ((L >> 5) & 1)
              + 8 * (L & 1) + 16 * ((L >> 1) & 1) + 32 * ((L >> 3) & 1)
              + 64 * bitrev3(p);
        int mb = (k <= 256) ? k : 512 - k;
        float wgt = 0.0f;
        if (mb >= 1 && mb < HI_BIN) {
            float f   = (float)mb * (3152.0f / 512.0f);
            float fsq = f * f;
            float num = 1.48693636e8f * fsq * fsq;
            float d1  = fsq + 424.36f;
            float d2  = fsq + 11599.29f;
            float d3  = fsq + 544496.41f;
            float d4  = fsq + 1.48693636e8f;
            float ratio = (num / (d1 * d4)) * rsqrtf(d2 * d3);
            wgt = ratio * ratio * 1.6141422e-9f;   // ratio^2 * 10^0.2 / (winpow*FS*nseg)
        }
        wt[p] = wgt;
        PINV(wt[p]);
    }
    // mid twiddles (c,s) = e^{-2pi i * bitrev3(r) * L / 512}
    v2f M[8];
#pragma unroll
    for (int r = 1; r < 8; ++r) {
        float ang = (float)(-2.0 * M_PI / 512.0) * (float)(bitrev3(r) * L);
        float s, c; __sincosf(ang, &s, &c);
        M[r] = (v2f){c, s};
        PINV(M[r]);
    }
    // cross-lane stage twiddles (m=32,16,8 only — lower stages now register-side)
    float c32, s32, c16, s16;
    __sincosf((float)(-2.0 * M_PI) * (float)(L & 31) / 64.0f, &s32, &c32);
    __sincosf((float)(-2.0 * M_PI) * (float)(L & 15) / 32.0f, &s16, &c16);
    v2f W32 = (v2f){c32, s32};
    v2f W16 = (v2f){c16, s16};
    v2f W8, g8v;
    if (L & 8) { float s, c; __sincosf((float)(-2.0 * M_PI) * (float)(L & 7) / 16.0f, &s, &c);
                 W8 = (v2f){c, s}; g8v = (v2f){-1.0f, -1.0f}; }
    else       { W8 = (v2f){1.0f, 0.0f}; g8v = (v2f){1.0f, 1.0f}; }
    PINV(W32); PINV(W16); PINV(W8); PINV(g8v);

    const float C707 = 0.70710678118654752f;
    v2f W81  = (v2f){C707, -C707};
    v2f W83  = (v2f){-C707, -C707};
    v2f WNIm = (v2f){1.0f, -1.0f};      // for cmulNI
    PINV(W81); PINV(W83); PINV(WNIm);

    v2f acc2 = (v2f){0.0f, 0.0f};
    const float* xb = x + (size_t)b * T_LEN;

    for (int p = winb; p < NPAIR; p += WPB) {
        const int s0 = 2 * p;
        v2f z[8];
        const float* p0 = xb + s0 * STEP + L;
        float a[8], bb[8];
#pragma unroll
        for (int r = 0; r < 8; ++r) a[r] = p0[64 * r];
        if (2 * p + 1 < NSEG) {               // wave-uniform; false only at p=765
#pragma unroll
            for (int r = 0; r < 8; ++r) bb[r] = p0[64 * r + STEP];
        } else {
#pragma unroll
            for (int r = 0; r < 8; ++r) bb[r] = 0.0f;
        }
#pragma unroll
        for (int r = 0; r < 8; ++r) {
            v2f zin = (v2f){a[r], bb[r]};
            z[r] = zin * wvp[r];
        }

        // ---- per-lane radix-2 DIF FFT-8 over registers (packed complex) ----
        {
            v2f d0 = z[0] - z[4]; z[0] += z[4];
            v2f d1 = z[1] - z[5]; z[1] += z[5];
            v2f d2 = z[2] - z[6]; z[2] += z[6];
            v2f d3 = z[3] - z[7]; z[3] += z[7];
            z[4] = d0;
            z[5] = cmul(d1, W81);
            z[6] = cmulNI(d2, WNIm);
            z[7] = cmul(d3, W83);
            v2f t;
            t = z[0] - z[2]; z[0] += z[2]; z[2] = t;
            t = z[1] - z[3]; z[1] += z[3]; z[3] = cmulNI(t, WNIm);
            t = z[4] - z[6]; z[4] += z[6]; z[6] = t;
            t = z[5] - z[7]; z[5] += z[7]; z[7] = cmulNI(t, WNIm);
#pragma unroll
            for (int g = 0; g < 8; g += 2) {
                t = z[g] - z[g + 1]; z[g] += z[g + 1]; z[g + 1] = t;
            }
        }

        // ---- mid twiddle ----
#pragma unroll
        for (int r = 1; r < 8; ++r) z[r] = cmul(z[r], M[r]);

        // ---- cross-lane stages m=32,16 (permlane swap tricks), m=8 (DPP) ----
#pragma unroll
        for (int q = 0; q < 8; q += 2) {
            float a0 = z[q].x, a1 = z[q].y, b0 = z[q + 1].x, b1 = z[q + 1].y;
            pswap32(a0, b0); pswap32(a1, b1);
            v2f A = (v2f){a0, a1}, B = (v2f){b0, b1};
            v2f s = A + B, d = A - B;
            z[q] = s; z[q + 1] = cmul(d, W32);
        }
        {
            const int qs[4] = {0, 1, 4, 5};
#pragma unroll
            for (int t2 = 0; t2 < 4; ++t2) {
                const int q = qs[t2];
                float a0 = z[q].x, a1 = z[q].y, b0 = z[q + 2].x, b1 = z[q + 2].y;
                pswap16(a0, b0); pswap16(a1, b1);
                v2f A = (v2f){a0, a1}, B = (v2f){b0, b1};
                v2f s = A + B, d = A - B;
                z[q] = s; z[q + 2] = cmul(d, W16);
            }
        }
#pragma unroll
        for (int q = 0; q < 8; ++q) {
            v2f pp = (v2f){dppf<0x128>(z[q].x), dppf<0x128>(z[q].y)};
            v2f n = g8v * z[q] + pp;
            z[q] = cmul(n, W8);
        }

        // ---- 8x8 transpose through LDS: (lane bits 0-2) <-> (reg index) ----
#pragma unroll
        for (int q = 0; q < 8; ++q) *(v2f*)(wptr + 528 * q) = z[q];
        v2f y[8];
#pragma unroll
        for (int q = 0; q < 8; ++q) y[q] = *(const v2f*)(rptr + 8 * q);

        // ---- register FFT-8 over old lane bits (k2 high bits), twiddle-free ----
        {
            v2f d0 = y[0] - y[4]; y[0] += y[4];
            v2f d1 = y[1] - y[5]; y[1] += y[5];
            v2f d2 = y[2] - y[6]; y[2] += y[6];
            v2f d3 = y[3] - y[7]; y[3] += y[7];
            y[4] = d0;
            y[5] = cmul(d1, W81);
            y[6] = cmulNI(d2, WNIm);
            y[7] = cmul(d3, W83);
            v2f t;
            t = y[0] - y[2]; y[0] += y[2]; y[2] = t;
            t = y[1] - y[3]; y[1] += y[3]; y[3] = cmulNI(t, WNIm);
            t = y[4] - y[6]; y[4] += y[6]; y[6] = t;
            t = y[5] - y[7]; y[5] += y[7]; y[7] = cmulNI(t, WNIm);
#pragma unroll
            for (int g = 0; g < 8; g += 2) {
                t = y[g] - y[g + 1]; y[g] += y[g + 1]; y[g + 1] = t;
            }
        }

        // ---- weighted energy ----
#pragma unroll
        for (int q = 0; q < 8; ++q) {
            v2f e = y[q] * y[q];
            acc2 += (v2f){wt[q], wt[q]} * e;
        }
    }

    float acc = acc2.x + acc2.y;
    // wave reduction -> one uncontended store per wave
#pragma unroll
    for (int off = 32; off >= 1; off >>= 1) acc += __shfl_xor(acc, off, 64);
    if (L == 0) ws[waveId] = acc;
}

__global__ void finalize_k(const float* __restrict__ ws, float* __restrict__ out) {
    __shared__ float red[256];
    int t = threadIdx.x;          // 256 threads
    int b = t & 63, g = t >> 6;   // 4 chunks of 32 partials per batch
    float s = 0.0f;
    for (int i = 0; i < 32; ++i) s += ws[b * 128 + g * 32 + i];
    red[t] = s;
    __syncthreads();
    if (t < 64) {
        float band = red[t] + red[t + 64] + red[t + 128] + red[t + 192];
        float lv = 10.0f * log10f(band);
#pragma unroll
        for (int off = 32; off >= 1; off >>= 1) lv += __shfl_xor(lv, off, 64);
        if (t == 0) out[0] = lv * (1.0f / 64.0f);
    }
}

extern "C" void kernel_launch(void* const* d_in, const int* in_sizes, int n_in,
                              void* d_out, int out_size, void* d_ws, size_t ws_size,
                              hipStream_t stream) {
    const float* x = (const float*)d_in[0];
    float* out = (float*)d_out;
    float* ws  = (float*)d_ws;
    fft_band_k<<<(NBATCH * WPB) / 4, 256, 0, stream>>>(x, ws);
    finalize_k<<<1, 256, 0, stream>>>(ws, out);
}

// Round 7
// 105.791 us; speedup vs baseline: 1.0804x; 1.0021x over previous
//
#include <hip/hip_runtime.h>
#include <math.h>

#ifndef M_PI
#define M_PI 3.14159265358979323846
#endif

#define T_LEN   262144
#define NBATCH  64
#define STEP    171
#define NSEG    1531          // (262144-512)/171 + 1
#define NPAIR   766           // ceil(1531/2); last pair has zero imag segment
#define WPB     128           // waves per batch -> 8192 waves total
#define HI_BIN  244           // exclusive upper band bin

typedef float v2f __attribute__((ext_vector_type(2)));
typedef float v4f __attribute__((ext_vector_type(4)));

__device__ __forceinline__ int bitrev3(int r) {
    return ((r & 1) << 2) | (r & 2) | ((r & 4) >> 2);
}

// ---- gfx950 cross-lane helpers (non-volatile: pure dataflow, lets the
// scheduler interleave the two independent pair-streams) ----
__device__ __forceinline__ void pswap32(float& a, float& b) {
    asm("v_permlane32_swap_b32 %0, %1" : "+v"(a), "+v"(b));
}
__device__ __forceinline__ void pswap16(float& a, float& b) {
    asm("v_permlane16_swap_b32 %0, %1" : "+v"(a), "+v"(b));
}
template <int CTRL>
__device__ __forceinline__ float dppf(float x) {   // DPP cross-lane (VALU pipe)
    return __int_as_float(__builtin_amdgcn_mov_dpp(__float_as_int(x), CTRL, 0xF, 0xF, true));
}

// complex rotate: z * (c + i s), w = (c, s) packed. 2 VOP3P instrs.
__device__ __forceinline__ v2f cmul(v2f z, v2f w) {
    v2f t, d;
    asm("v_pk_mul_f32 %0, %1, %2 op_sel_hi:[1,0]"
        : "=v"(t) : "v"(z), "v"(w));
    asm("v_pk_fma_f32 %0, %1, %2, %3 op_sel:[1,1,0] op_sel_hi:[0,1,1] neg_lo:[1,0,0]"
        : "=v"(d) : "v"(z), "v"(w), "v"(t));
    return d;
}
// z * (-i) = (y, -x): single pk_mul with op_sel; m = (1.0, -1.0)
__device__ __forceinline__ v2f cmulNI(v2f z, v2f m) {
    v2f d;
    asm("v_pk_mul_f32 %0, %1, %2 op_sel:[1,0] op_sel_hi:[0,1]"
        : "=v"(d) : "v"(z), "v"(m));
    return d;
}

// volatile pin: opaque def -> cannot be rematerialized or sunk into the loop
#define PINV(x) asm volatile("" : "+v"(x))

// ws layout: [0, 8192) per-wave partial band sums
__global__ __launch_bounds__(256, 3) void fft_band_k(const float* __restrict__ x,
                                                     float* __restrict__ ws) {
    // per-wave transpose scratch: 2 slots x (8 rows x 528 B) = 8448 B/wave
    __shared__ __align__(16) char ldsc[4 * 8448];

    const int L      = threadIdx.x & 63;
    const int wib    = threadIdx.x >> 6;
    const int waveId = (int)(blockIdx.x * 256 + threadIdx.x) >> 6;
    const int b      = waveId >> 7;           // / WPB
    const int winb   = waveId & (WPB - 1);

    char* base0 = ldsc + wib * 8448;
    char* base1 = base0 + 4224;
    const int woff = 8 * L;                             // write: col 8L, +528*q imm
    const int roff = 528 * (L & 7) + 8 * (L & 0x38);    // read: row base, +8q imm (64B run)

    // ---- per-wave loop-invariant constants (volatile-pinned vs remat) ----
    v2f wvp[8];
#pragma unroll
    for (int r = 0; r < 8; ++r) {
        float n = (float)(L + 64 * r);
        float w = 0.54f - 0.46f * __cosf((float)(2.0 * M_PI / 512.0) * n);
        wvp[r] = (v2f){w, w};
        PINV(wvp[r]);
    }
    // weights at final (reg rho, lane L): k = L2 + 2*L4 + 4*L5 + 8*L0 + 16*L1 + 32*L3 + 64*bitrev3(rho)
    float wt[8];
#pragma unroll
    for (int p = 0; p < 8; ++p) {
        int k = ((L >> 2) & 1) + 2 * ((L >> 4) & 1) + 4 * ((L >> 5) & 1)
              + 8 * (L & 1) + 16 * ((L >> 1) & 1) + 32 * ((L >> 3) & 1)
              + 64 * bitrev3(p);
        int mb = (k <= 256) ? k : 512 - k;
        float wgt = 0.0f;
        if (mb >= 1 && mb < HI_BIN) {
            float f   = (float)mb * (3152.0f / 512.0f);
            float fsq = f * f;
            float num = 1.48693636e8f * fsq * fsq;
            float d1  = fsq + 424.36f;
            float d2  = fsq + 11599.29f;
            float d3  = fsq + 544496.41f;
            float d4  = fsq + 1.48693636e8f;
            float ratio = (num / (d1 * d4)) * rsqrtf(d2 * d3);
            wgt = ratio * ratio * 1.6141422e-9f;   // ratio^2 * 10^0.2 / (winpow*FS*nseg)
        }
        wt[p] = wgt;
        PINV(wt[p]);
    }
    // mid twiddles (c,s) = e^{-2pi i * bitrev3(r) * L / 512}
    v2f M[8];
#pragma unroll
    for (int r = 1; r < 8; ++r) {
        float ang = (float)(-2.0 * M_PI / 512.0) * (float)(bitrev3(r) * L);
        float s, c; __sincosf(ang, &s, &c);
        M[r] = (v2f){c, s};
        PINV(M[r]);
    }
    // cross-lane stage twiddles (m=32,16,8 only — lower stages are register-side)
    float c32, s32, c16, s16;
    __sincosf((float)(-2.0 * M_PI) * (float)(L & 31) / 64.0f, &s32, &c32);
    __sincosf((float)(-2.0 * M_PI) * (float)(L & 15) / 32.0f, &s16, &c16);
    v2f W32 = (v2f){c32, s32};
    v2f W16 = (v2f){c16, s16};
    v2f W8, g8v;
    if (L & 8) { float s, c; __sincosf((float)(-2.0 * M_PI) * (float)(L & 7) / 16.0f, &s, &c);
                 W8 = (v2f){c, s}; g8v = (v2f){-1.0f, -1.0f}; }
    else       { W8 = (v2f){1.0f, 0.0f}; g8v = (v2f){1.0f, 1.0f}; }
    PINV(W32); PINV(W16); PINV(W8); PINV(g8v);

    const float C707 = 0.70710678118654752f;
    v2f W81  = (v2f){C707, -C707};
    v2f W83  = (v2f){-C707, -C707};
    v2f WNIm = (v2f){1.0f, -1.0f};      // for cmulNI
    PINV(W81); PINV(W83); PINV(WNIm);

    v2f accA = (v2f){0.0f, 0.0f};
    v2f accB = (v2f){0.0f, 0.0f};
    const float* xb = x + (size_t)b * T_LEN;

    // one segment-pair: load, FFT-512, weighted energy into acc
    auto body = [&](int p, char* bse, v2f& acc2) __attribute__((always_inline)) {
        v2f z[8];
        const float* p0 = xb + (2 * p) * STEP + L;
        float a[8], bb[8];
#pragma unroll
        for (int r = 0; r < 8; ++r) a[r] = p0[64 * r];
        if (2 * p + 1 < NSEG) {               // wave-uniform; false only at p=765
#pragma unroll
            for (int r = 0; r < 8; ++r) bb[r] = p0[64 * r + STEP];
        } else {
#pragma unroll
            for (int r = 0; r < 8; ++r) bb[r] = 0.0f;
        }
#pragma unroll
        for (int r = 0; r < 8; ++r) z[r] = (v2f){a[r], bb[r]} * wvp[r];

        // per-lane radix-2 DIF FFT-8 over registers
        {
            v2f d0 = z[0] - z[4]; z[0] += z[4];
            v2f d1 = z[1] - z[5]; z[1] += z[5];
            v2f d2 = z[2] - z[6]; z[2] += z[6];
            v2f d3 = z[3] - z[7]; z[3] += z[7];
            z[4] = d0;
            z[5] = cmul(d1, W81);
            z[6] = cmulNI(d2, WNIm);
            z[7] = cmul(d3, W83);
            v2f t;
            t = z[0] - z[2]; z[0] += z[2]; z[2] = t;
            t = z[1] - z[3]; z[1] += z[3]; z[3] = cmulNI(t, WNIm);
            t = z[4] - z[6]; z[4] += z[6]; z[6] = t;
            t = z[5] - z[7]; z[5] += z[7]; z[7] = cmulNI(t, WNIm);
#pragma unroll
            for (int g = 0; g < 8; g += 2) {
                t = z[g] - z[g + 1]; z[g] += z[g + 1]; z[g + 1] = t;
            }
        }

        // mid twiddle
#pragma unroll
        for (int r = 1; r < 8; ++r) z[r] = cmul(z[r], M[r]);

        // cross-lane m=32 (permlane32 swap trick)
#pragma unroll
        for (int q = 0; q < 8; q += 2) {
            float a0 = z[q].x, a1 = z[q].y, b0 = z[q + 1].x, b1 = z[q + 1].y;
            pswap32(a0, b0); pswap32(a1, b1);
            v2f A = (v2f){a0, a1}, B = (v2f){b0, b1};
            v2f s = A + B, d = A - B;
            z[q] = s; z[q + 1] = cmul(d, W32);
        }
        // m=16 (permlane16 swap trick), pairs (q, q+2)
        {
            const int qs[4] = {0, 1, 4, 5};
#pragma unroll
            for (int t2 = 0; t2 < 4; ++t2) {
                const int q = qs[t2];
                float a0 = z[q].x, a1 = z[q].y, b0 = z[q + 2].x, b1 = z[q + 2].y;
                pswap16(a0, b0); pswap16(a1, b1);
                v2f A = (v2f){a0, a1}, B = (v2f){b0, b1};
                v2f s = A + B, d = A - B;
                z[q] = s; z[q + 2] = cmul(d, W16);
            }
        }
        // m=8: DPP row_ror:8 == lane xor 8
#pragma unroll
        for (int q = 0; q < 8; ++q) {
            v2f pp = (v2f){dppf<0x128>(z[q].x), dppf<0x128>(z[q].y)};
            v2f n = g8v * z[q] + pp;
            z[q] = cmul(n, W8);
        }

        // 8x8 transpose through LDS (write col-strided, read 64B runs as b128)
        {
            char* w0 = bse + woff;
            char* w1 = w0 + 1056;
            char* w2 = w0 + 2112;
            char* w3 = w0 + 3168;
            *(v2f*)(w0) = z[0]; *(v2f*)(w0 + 528) = z[1];
            *(v2f*)(w1) = z[2]; *(v2f*)(w1 + 528) = z[3];
            *(v2f*)(w2) = z[4]; *(v2f*)(w2 + 528) = z[5];
            *(v2f*)(w3) = z[6]; *(v2f*)(w3 + 528) = z[7];
        }
        v2f y[8];
        {
            const char* rp = bse + roff;
            v4f q0 = *(const v4f*)(rp);
            v4f q1 = *(const v4f*)(rp + 16);
            v4f q2 = *(const v4f*)(rp + 32);
            v4f q3 = *(const v4f*)(rp + 48);
            y[0] = (v2f){q0.x, q0.y}; y[1] = (v2f){q0.z, q0.w};
            y[2] = (v2f){q1.x, q1.y}; y[3] = (v2f){q1.z, q1.w};
            y[4] = (v2f){q2.x, q2.y}; y[5] = (v2f){q2.z, q2.w};
            y[6] = (v2f){q3.x, q3.y}; y[7] = (v2f){q3.z, q3.w};
        }

        // register FFT-8 over old lane bits (twiddle-free structure)
        {
            v2f d0 = y[0] - y[4]; y[0] += y[4];
            v2f d1 = y[1] - y[5]; y[1] += y[5];
            v2f d2 = y[2] - y[6]; y[2] += y[6];
            v2f d3 = y[3] - y[7]; y[3] += y[7];
            y[4] = d0;
            y[5] = cmul(d1, W81);
            y[6] = cmulNI(d2, WNIm);
            y[7] = cmul(d3, W83);
            v2f t;
            t = y[0] - y[2]; y[0] += y[2]; y[2] = t;
            t = y[1] - y[3]; y[1] += y[3]; y[3] = cmulNI(t, WNIm);
            t = y[4] - y[6]; y[4] += y[6]; y[6] = t;
            t = y[5] - y[7]; y[5] += y[7]; y[7] = cmulNI(t, WNIm);
#pragma unroll
            for (int g = 0; g < 8; g += 2) {
                t = y[g] - y[g + 1]; y[g] += y[g + 1]; y[g + 1] = t;
            }
        }

        // weighted energy
#pragma unroll
        for (int q = 0; q < 8; ++q) {
            v2f e = y[q] * y[q];
            acc2 += (v2f){wt[q], wt[q]} * e;
        }
    };

    int p = winb;
    // two independent pair-streams per iteration (separate LDS slots + accs)
    for (; p + WPB < NPAIR; p += 2 * WPB) {
        body(p, base0, accA);
        body(p + WPB, base1, accB);
    }
    if (p < NPAIR) body(p, base0, accA);

    v2f acc2 = accA + accB;
    float acc = acc2.x + acc2.y;
    // wave reduction -> one uncontended store per wave
#pragma unroll
    for (int off = 32; off >= 1; off >>= 1) acc += __shfl_xor(acc, off, 64);
    if (L == 0) ws[waveId] = acc;
}

__global__ void finalize_k(const float* __restrict__ ws, float* __restrict__ out) {
    __shared__ float red[256];
    int t = threadIdx.x;          // 256 threads
    int b = t & 63, g = t >> 6;   // 4 chunks of 32 partials per batch
    float s = 0.0f;
    for (int i = 0; i < 32; ++i) s += ws[b * 128 + g * 32 + i];
    red[t] = s;
    __syncthreads();
    if (t < 64) {
        float band = red[t] + red[t + 64] + red[t + 128] + red[t + 192];
        float lv = 10.0f * log10f(band);
#pragma unroll
        for (int off = 32; off >= 1; off >>= 1) lv += __shfl_xor(lv, off, 64);
        if (t == 0) out[0] = lv * (1.0f / 64.0f);
    }
}

extern "C" void kernel_launch(void* const* d_in, const int* in_sizes, int n_in,
                              void* d_out, int out_size, void* d_ws, size_t ws_size,
                              hipStream_t stream) {
    const float* x = (const float*)d_in[0];
    float* out = (float*)d_out;
    float* ws  = (float*)d_ws;
    fft_band_k<<<(NBATCH * WPB) / 4, 256, 0, stream>>>(x, ws);
    finalize_k<<<1, 256, 0, stream>>>(ws, out);
}